// Round 4
// baseline (1821.231 us; speedup 1.0000x reference)
//
#include <hip/hip_runtime.h>
#include <math.h>

#define TOKENS 16384   // B*S = 4*4096
#define DDIM   4096
#define NEXP   128
#define TOPK   8

#define TM     64      // tokens per block
#define BK     32      // K chunk
#define STR    33      // LDS row stride (floats): wb reads conflict-free, xa 2-way (free)
#define NC     (DDIM / BK)

#define DELTA  3.0e-4f // flag threshold on min adjacent top-9 fp32 logit gap
#define FCAP   8192    // max flagged tokens

// ws layout: [0] u32 count ; [64..] u32 token list (FCAP entries)

// ================= fp32 GEMM + softmax + top-8 + gap-flag =================
__global__ __launch_bounds__(256, 4)
void gemm_topk(const float* __restrict__ x,
               const float* __restrict__ W,
               const float* __restrict__ b,
               float* __restrict__ out,
               unsigned int* __restrict__ flagc,
               unsigned int* __restrict__ flagl)
{
    // phase 1: xs[64][33] + ws[128][33] = 25.3 KB ; phase 2: lg[64][128] f32 = 32 KB
    __shared__ __align__(16) float smem[TM * NEXP];
    float* xs = smem;
    float* ws = smem + TM * STR;
    float* lg = smem;

    const int t    = threadIdx.x;
    const int tok0 = blockIdx.x * TM;
    const int el   = t >> 3;   // expert group: experts el*4 + j
    const int tg   = t & 7;    // token group:  tokens  tg*8 + i

    float acc[8][4];
    #pragma unroll
    for (int i = 0; i < 8; ++i)
        #pragma unroll
        for (int j = 0; j < 4; ++j) acc[i][j] = 0.0f;

    float4 gx[2], gw[4];

    // prefetch chunk 0: x 512 f4 (q=t+256r), W 1024 f4 (q=t+256r)
    {
        #pragma unroll
        for (int r = 0; r < 2; ++r) {
            const int q = t + r * 256;
            gx[r] = *reinterpret_cast<const float4*>(
                &x[(size_t)(tok0 + (q >> 3)) * DDIM + (q & 7) * 4]);
        }
        #pragma unroll
        for (int r = 0; r < 4; ++r) {
            const int q = t + r * 256;
            gw[r] = *reinterpret_cast<const float4*>(
                &W[(size_t)(q >> 3) * DDIM + (q & 7) * 4]);
        }
    }

    #pragma unroll 1
    for (int c = 0; c < NC; ++c) {
        __syncthreads();
        #pragma unroll
        for (int r = 0; r < 2; ++r) {
            const int q = t + r * 256;
            *reinterpret_cast<float4*>(&xs[(q >> 3) * STR + (q & 7) * 4]) = gx[r];
        }
        #pragma unroll
        for (int r = 0; r < 4; ++r) {
            const int q = t + r * 256;
            *reinterpret_cast<float4*>(&ws[(q >> 3) * STR + (q & 7) * 4]) = gw[r];
        }
        __syncthreads();

        if (c + 1 < NC) {
            const int k0 = (c + 1) * BK;
            #pragma unroll
            for (int r = 0; r < 2; ++r) {
                const int q = t + r * 256;
                gx[r] = *reinterpret_cast<const float4*>(
                    &x[(size_t)(tok0 + (q >> 3)) * DDIM + k0 + (q & 7) * 4]);
            }
            #pragma unroll
            for (int r = 0; r < 4; ++r) {
                const int q = t + r * 256;
                gw[r] = *reinterpret_cast<const float4*>(
                    &W[(size_t)(q >> 3) * DDIM + k0 + (q & 7) * 4]);
            }
        }

        #pragma unroll 2
        for (int kk = 0; kk < BK; kk += 4) {
            float4 xa[8], wb[4];
            #pragma unroll
            for (int i = 0; i < 8; ++i)
                xa[i] = *reinterpret_cast<const float4*>(&xs[(tg * 8 + i) * STR + kk]);
            #pragma unroll
            for (int j = 0; j < 4; ++j)
                wb[j] = *reinterpret_cast<const float4*>(&ws[(el * 4 + j) * STR + kk]);
            #pragma unroll
            for (int i = 0; i < 8; ++i) {
                #pragma unroll
                for (int j = 0; j < 4; ++j) {
                    acc[i][j] = fmaf(xa[i].x, wb[j].x, acc[i][j]);
                    acc[i][j] = fmaf(xa[i].y, wb[j].y, acc[i][j]);
                    acc[i][j] = fmaf(xa[i].z, wb[j].z, acc[i][j]);
                    acc[i][j] = fmaf(xa[i].w, wb[j].w, acc[i][j]);
                }
            }
        }
    }

    // logits -> LDS
    __syncthreads();
    #pragma unroll
    for (int i = 0; i < 8; ++i)
        #pragma unroll
        for (int j = 0; j < 4; ++j)
            lg[(tg * 8 + i) * NEXP + el * 4 + j] = acc[i][j];
    __syncthreads();

    // per-wave softmax + top-9 (8 written, 9th for gap certificate)
    const int lane = t & 63;
    const int wv   = t >> 6;

    for (int it = 0; it < 16; ++it) {
        const int m  = wv * 16 + it;
        const int e1 = lane, e2 = lane + 64;
        const float v1 = lg[m * NEXP + e1] + b[e1];
        const float v2 = lg[m * NEXP + e2] + b[e2];

        float mx = fmaxf(v1, v2);
        #pragma unroll
        for (int off = 32; off > 0; off >>= 1)
            mx = fmaxf(mx, __shfl_xor(mx, off, 64));

        float s = expf(v1 - mx) + expf(v2 - mx);
        #pragma unroll
        for (int off = 32; off > 0; off >>= 1)
            s += __shfl_xor(s, off, 64);

        float w1 = v1, w2 = v2;
        float prev = 0.0f, mingap = 1e30f;
        for (int r = 0; r < TOPK + 1; ++r) {
            float bv = w1; int bi = e1;
            if (w2 > bv) { bv = w2; bi = e2; }   // e2>e1: tie keeps e1
            #pragma unroll
            for (int off = 32; off > 0; off >>= 1) {
                float ov = __shfl_xor(bv, off, 64);
                int   oi = __shfl_xor(bi, off, 64);
                if (ov > bv || (ov == bv && oi < bi)) { bv = ov; bi = oi; }
            }
            if (r > 0) mingap = fminf(mingap, prev - bv);
            prev = bv;
            if (r < TOPK && lane == 0) {
                const size_t T = (size_t)tok0 + m;
                out[T * TOPK + r] = expf(bv - mx) / s;
                out[(size_t)TOKENS * TOPK + T * TOPK + r] = (float)bi;
            }
            if (bi == e1) w1 = -1e30f;
            if (bi == e2) w2 = -1e30f;
        }
        if (lane == 0 && mingap < DELTA) {
            unsigned int pos = atomicAdd(flagc, 1u);
            if (pos < FCAP) flagl[pos] = (unsigned int)(tok0 + m);
        }
    }
}

// ================= fp64 refine for flagged tokens =================
__global__ __launch_bounds__(256, 2)
void refine(const float* __restrict__ x,
            const float* __restrict__ W,
            const float* __restrict__ b,
            float* __restrict__ out,
            const unsigned int* __restrict__ flagc,
            const unsigned int* __restrict__ flagl)
{
    __shared__ __align__(16) float  xrow[DDIM];     // 16 KB
    __shared__ double psum[256];                    // 2 KB
    __shared__ double dlog[NEXP];                   // 1 KB

    const int t = threadIdx.x;
    unsigned int n = *flagc;
    if (n > FCAP) n = FCAP;

    for (unsigned int idx = blockIdx.x; idx < n; idx += gridDim.x) {
        const unsigned int tok = flagl[idx];

        __syncthreads();   // protect xrow reuse across iterations
        // stage x row
        #pragma unroll
        for (int r = 0; r < 4; ++r) {
            const int q = t + r * 256;
            *reinterpret_cast<float4*>(&xrow[q * 4]) = *reinterpret_cast<const float4*>(
                &x[(size_t)tok * DDIM + q * 4]);
        }
        __syncthreads();

        // fp64 dot: expert e = t>>1, K-half = t&1, 4 interleaved partials
        const int e  = t >> 1;
        const int h  = t & 1;
        const int k0 = h * (DDIM / 2);
        double s0 = 0.0, s1 = 0.0, s2 = 0.0, s3 = 0.0;
        const float* wr = &W[(size_t)e * DDIM + k0];
        const float* xr = &xrow[k0];
        for (int k = 0; k < DDIM / 2; k += 4) {
            s0 = fma((double)xr[k],     (double)wr[k],     s0);
            s1 = fma((double)xr[k + 1], (double)wr[k + 1], s1);
            s2 = fma((double)xr[k + 2], (double)wr[k + 2], s2);
            s3 = fma((double)xr[k + 3], (double)wr[k + 3], s3);
        }
        psum[t] = ((s0 + s1) + (s2 + s3));
        __syncthreads();
        if (t < NEXP)
            dlog[t] = (psum[2 * t] + psum[2 * t + 1]) + (double)b[t];
        __syncthreads();

        // wave 0: fp64 softmax + top-8, overwrite outputs
        if (t < 64) {
            const int lane = t;
            const int e1 = lane, e2 = lane + 64;
            const double v1 = dlog[e1], v2 = dlog[e2];

            double mx = fmax(v1, v2);
            #pragma unroll
            for (int off = 32; off > 0; off >>= 1)
                mx = fmax(mx, __shfl_xor(mx, off, 64));

            double s = exp(v1 - mx) + exp(v2 - mx);
            #pragma unroll
            for (int off = 32; off > 0; off >>= 1)
                s += __shfl_xor(s, off, 64);

            double w1 = v1, w2 = v2;
            for (int r = 0; r < TOPK; ++r) {
                double bv = w1; int bi = e1;
                if (w2 > bv) { bv = w2; bi = e2; }
                #pragma unroll
                for (int off = 32; off > 0; off >>= 1) {
                    double ov = __shfl_xor(bv, off, 64);
                    int    oi = __shfl_xor(bi, off, 64);
                    if (ov > bv || (ov == bv && oi < bi)) { bv = ov; bi = oi; }
                }
                if (lane == 0) {
                    const size_t T = (size_t)tok;
                    out[T * TOPK + r] = (float)(exp(bv - mx) / s);
                    out[(size_t)TOKENS * TOPK + T * TOPK + r] = (float)bi;
                }
                if (bi == e1) w1 = -1e300;
                if (bi == e2) w2 = -1e300;
            }
        }
    }
}

extern "C" void kernel_launch(void* const* d_in, const int* in_sizes, int n_in,
                              void* d_out, int out_size, void* d_ws, size_t ws_size,
                              hipStream_t stream) {
    const float* x = (const float*)d_in[0];
    const float* W = (const float*)d_in[1];
    const float* b = (const float*)d_in[2];
    float* out = (float*)d_out;

    unsigned int* flagc = (unsigned int*)d_ws;
    unsigned int* flagl = (unsigned int*)((char*)d_ws + 64);

    hipMemsetAsync(flagc, 0, 4, stream);
    hipLaunchKernelGGL(gemm_topk, dim3(TOKENS / TM), dim3(256), 0, stream,
                       x, W, b, out, flagc, flagl);
    hipLaunchKernelGGL(refine, dim3(128), dim3(256), 0, stream,
                       x, W, b, out, flagc, flagl);
}

// Round 9
// 712.716 us; speedup vs baseline: 2.5553x; 2.5553x over previous
//
#include <hip/hip_runtime.h>
#include <math.h>

#define TOKENS 16384   // B*S
#define DDIM   4096
#define NEXP   128
#define TOPK   8

#define DELTA  3.0e-4f // flag threshold on min adjacent top-9 logit gap
#define FCAP   8192

typedef __bf16 bf16x8 __attribute__((ext_vector_type(8)));
typedef float  f32x4  __attribute__((ext_vector_type(4)));

union FragU { uint4 u; bf16x8 v; };
union FU    { float f; unsigned int u; };

// split 8 consecutive f32 (p,q) into hi/lo bf16 packs (truncation both levels)
__device__ __forceinline__ void split8(float4 p, float4 q, uint4& hi, uint4& lo) {
    float e[8] = {p.x, p.y, p.z, p.w, q.x, q.y, q.z, q.w};
    unsigned int hb[8], lb[8];
    #pragma unroll
    for (int i = 0; i < 8; ++i) {
        FU t; t.f = e[i];
        FU h; h.u = t.u & 0xFFFF0000u;       // hi = truncated bf16 as f32
        FU r; r.f = e[i] - h.f;              // exact residual
        hb[i] = t.u; lb[i] = r.u;
    }
    hi.x = (hb[0] >> 16) | (hb[1] & 0xFFFF0000u);
    hi.y = (hb[2] >> 16) | (hb[3] & 0xFFFF0000u);
    hi.z = (hb[4] >> 16) | (hb[5] & 0xFFFF0000u);
    hi.w = (hb[6] >> 16) | (hb[7] & 0xFFFF0000u);
    lo.x = (lb[0] >> 16) | (lb[1] & 0xFFFF0000u);
    lo.y = (lb[2] >> 16) | (lb[3] & 0xFFFF0000u);
    lo.z = (lb[4] >> 16) | (lb[5] & 0xFFFF0000u);
    lo.w = (lb[6] >> 16) | (lb[7] & 0xFFFF0000u);
}

// ====== pre-kernel: W (f32, [128][4096]) -> frag-major bf16 hi/lo image ======
// wimg frag f = ((c*8 + j)*2 + h), 64 uint4 per frag (lane l holds
// W_h[j*16 + (l&15)][c*32 + (l>>4)*8 + 0..7] packed as bf16x8)
__global__ __launch_bounds__(256)
void split_w(const float* __restrict__ W, uint4* __restrict__ wimg)
{
    const int c  = blockIdx.x;          // 128 K-chunks of 32
    const int t  = threadIdx.x;
    const int l  = t & 63;
    const int jj = t >> 6;              // 0..3
    #pragma unroll
    for (int loop = 0; loop < 2; ++loop) {
        const int j = loop * 4 + jj;    // expert tile 0..7
        const int e = j * 16 + (l & 15);
        const int k = c * 32 + (l >> 4) * 8;
        const float4* wp = reinterpret_cast<const float4*>(&W[(size_t)e * DDIM + k]);
        uint4 hi, lo;
        split8(wp[0], wp[1], hi, lo);
        wimg[((size_t)(c * 8 + j) * 2 + 0) * 64 + l] = hi;
        wimg[((size_t)(c * 8 + j) * 2 + 1) * 64 + l] = lo;
    }
}

// ====== main: split-bf16 MFMA GEMM + softmax + top-8 + gap flag ======
// block = 32 tokens, 4 waves; wave w owns expert tiles 2w, 2w+1 (32 experts)
__global__ __launch_bounds__(256, 2)
void gemm_mfma(const float* __restrict__ x,
               const uint4* __restrict__ wimg,
               const float* __restrict__ b,
               float* __restrict__ out,
               unsigned int* __restrict__ flagc,
               unsigned int* __restrict__ flagl)
{
    __shared__ float lg[32 * NEXP];     // 16 KB logits
    const int t    = threadIdx.x;
    const int l    = t & 63;
    const int w    = t >> 6;
    const int tok0 = blockIdx.x * 32;

    const size_t row0 = (size_t)(tok0 + (l & 15)) * DDIM;  // token tile 0
    const size_t row1 = row0 + (size_t)16 * DDIM;          // token tile 1
    const int    kg   = (l >> 4) * 8;
    const int    j0   = 2 * w;

    f32x4 acc[2][2] = {};   // [token-tile][expert-tile]

    #pragma unroll 2
    for (int c = 0; c < 128; ++c) {
        const int koff = c * 32 + kg;
        // B-frags: direct from pre-permuted wimg (L2-resident), coalesced
        FragU b0h, b0l, b1h, b1l;
        b0h.u = wimg[((size_t)(c * 8 + j0) * 2 + 0) * 64 + l];
        b0l.u = wimg[((size_t)(c * 8 + j0) * 2 + 1) * 64 + l];
        b1h.u = wimg[((size_t)(c * 8 + j0 + 1) * 2 + 0) * 64 + l];
        b1l.u = wimg[((size_t)(c * 8 + j0 + 1) * 2 + 1) * 64 + l];
        // A-frags: direct per-lane global loads + in-register split
        const float4* xp0 = reinterpret_cast<const float4*>(&x[row0 + koff]);
        const float4* xp1 = reinterpret_cast<const float4*>(&x[row1 + koff]);
        float4 p0 = xp0[0], q0 = xp0[1];
        float4 p1 = xp1[0], q1 = xp1[1];
        FragU a0h, a0l, a1h, a1l;
        split8(p0, q0, a0h.u, a0l.u);
        split8(p1, q1, a1h.u, a1l.u);

        acc[0][0] = __builtin_amdgcn_mfma_f32_16x16x32_bf16(a0h.v, b0h.v, acc[0][0], 0, 0, 0);
        acc[0][0] = __builtin_amdgcn_mfma_f32_16x16x32_bf16(a0h.v, b0l.v, acc[0][0], 0, 0, 0);
        acc[0][0] = __builtin_amdgcn_mfma_f32_16x16x32_bf16(a0l.v, b0h.v, acc[0][0], 0, 0, 0);

        acc[0][1] = __builtin_amdgcn_mfma_f32_16x16x32_bf16(a0h.v, b1h.v, acc[0][1], 0, 0, 0);
        acc[0][1] = __builtin_amdgcn_mfma_f32_16x16x32_bf16(a0h.v, b1l.v, acc[0][1], 0, 0, 0);
        acc[0][1] = __builtin_amdgcn_mfma_f32_16x16x32_bf16(a0l.v, b1h.v, acc[0][1], 0, 0, 0);

        acc[1][0] = __builtin_amdgcn_mfma_f32_16x16x32_bf16(a1h.v, b0h.v, acc[1][0], 0, 0, 0);
        acc[1][0] = __builtin_amdgcn_mfma_f32_16x16x32_bf16(a1h.v, b0l.v, acc[1][0], 0, 0, 0);
        acc[1][0] = __builtin_amdgcn_mfma_f32_16x16x32_bf16(a1l.v, b0h.v, acc[1][0], 0, 0, 0);

        acc[1][1] = __builtin_amdgcn_mfma_f32_16x16x32_bf16(a1h.v, b1h.v, acc[1][1], 0, 0, 0);
        acc[1][1] = __builtin_amdgcn_mfma_f32_16x16x32_bf16(a1h.v, b1l.v, acc[1][1], 0, 0, 0);
        acc[1][1] = __builtin_amdgcn_mfma_f32_16x16x32_bf16(a1l.v, b1h.v, acc[1][1], 0, 0, 0);
    }

    // C/D layout (m89-verified): col = lane&15 (expert), row = (lane>>4)*4 + reg (token)
    #pragma unroll
    for (int tt = 0; tt < 2; ++tt)
        #pragma unroll
        for (int je = 0; je < 2; ++je)
            #pragma unroll
            for (int r = 0; r < 4; ++r)
                lg[(tt * 16 + (l >> 4) * 4 + r) * NEXP + (j0 + je) * 16 + (l & 15)]
                    = acc[tt][je][r];
    __syncthreads();

    // per-wave softmax + top-9 (8 written, 9th for gap certificate)
    for (int it = 0; it < 8; ++it) {
        const int m  = w * 8 + it;
        const int e1 = l, e2 = l + 64;
        const float v1 = lg[m * NEXP + e1] + b[e1];
        const float v2 = lg[m * NEXP + e2] + b[e2];

        float mx = fmaxf(v1, v2);
        #pragma unroll
        for (int off = 32; off > 0; off >>= 1)
            mx = fmaxf(mx, __shfl_xor(mx, off, 64));

        float s = expf(v1 - mx) + expf(v2 - mx);
        #pragma unroll
        for (int off = 32; off > 0; off >>= 1)
            s += __shfl_xor(s, off, 64);

        float w1 = v1, w2 = v2;
        float prev = 0.0f, mingap = 1e30f;
        for (int r = 0; r < TOPK + 1; ++r) {
            float bv = w1; int bi = e1;
            if (w2 > bv) { bv = w2; bi = e2; }   // e2>e1: tie keeps e1
            #pragma unroll
            for (int off = 32; off > 0; off >>= 1) {
                float ov = __shfl_xor(bv, off, 64);
                int   oi = __shfl_xor(bi, off, 64);
                if (ov > bv || (ov == bv && oi < bi)) { bv = ov; bi = oi; }
            }
            if (r > 0) mingap = fminf(mingap, prev - bv);
            prev = bv;
            if (r < TOPK && l == 0) {
                const size_t T = (size_t)tok0 + m;
                out[T * TOPK + r] = expf(bv - mx) / s;
                out[(size_t)TOKENS * TOPK + T * TOPK + r] = (float)bi;
            }
            if (bi == e1) w1 = -1e30f;
            if (bi == e2) w2 = -1e30f;
        }
        if (l == 0 && mingap < DELTA) {
            unsigned int pos = atomicAdd(flagc, 1u);
            if (pos < FCAP) flagl[pos] = (unsigned int)(tok0 + m);
        }
    }
}

// ====== fp64 refine for flagged tokens (verified R4) ======
__global__ __launch_bounds__(256, 2)
void refine(const float* __restrict__ x,
            const float* __restrict__ W,
            const float* __restrict__ b,
            float* __restrict__ out,
            const unsigned int* __restrict__ flagc,
            const unsigned int* __restrict__ flagl)
{
    __shared__ __align__(16) float xrow[DDIM];
    __shared__ double psum[256];
    __shared__ double dlog[NEXP];

    const int t = threadIdx.x;
    unsigned int n = *flagc;
    if (n > FCAP) n = FCAP;

    for (unsigned int idx = blockIdx.x; idx < n; idx += gridDim.x) {
        const unsigned int tok = flagl[idx];
        __syncthreads();
        #pragma unroll
        for (int r = 0; r < 4; ++r) {
            const int q = t + r * 256;
            *reinterpret_cast<float4*>(&xrow[q * 4]) =
                *reinterpret_cast<const float4*>(&x[(size_t)tok * DDIM + q * 4]);
        }
        __syncthreads();

        const int e  = t >> 1;
        const int h  = t & 1;
        const int k0 = h * (DDIM / 2);
        double s0 = 0.0, s1 = 0.0, s2 = 0.0, s3 = 0.0;
        const float* wr = &W[(size_t)e * DDIM + k0];
        const float* xr = &xrow[k0];
        for (int k = 0; k < DDIM / 2; k += 4) {
            s0 = fma((double)xr[k],     (double)wr[k],     s0);
            s1 = fma((double)xr[k + 1], (double)wr[k + 1], s1);
            s2 = fma((double)xr[k + 2], (double)wr[k + 2], s2);
            s3 = fma((double)xr[k + 3], (double)wr[k + 3], s3);
        }
        psum[t] = ((s0 + s1) + (s2 + s3));
        __syncthreads();
        if (t < NEXP)
            dlog[t] = (psum[2 * t] + psum[2 * t + 1]) + (double)b[t];
        __syncthreads();

        if (t < 64) {
            const int lane = t;
            const int e1 = lane, e2 = lane + 64;
            const double v1 = dlog[e1], v2 = dlog[e2];
            double mx = fmax(v1, v2);
            #pragma unroll
            for (int off = 32; off > 0; off >>= 1)
                mx = fmax(mx, __shfl_xor(mx, off, 64));
            double s = exp(v1 - mx) + exp(v2 - mx);
            #pragma unroll
            for (int off = 32; off > 0; off >>= 1)
                s += __shfl_xor(s, off, 64);
            double w1 = v1, w2 = v2;
            for (int r = 0; r < TOPK; ++r) {
                double bv = w1; int bi = e1;
                if (w2 > bv) { bv = w2; bi = e2; }
                #pragma unroll
                for (int off = 32; off > 0; off >>= 1) {
                    double ov = __shfl_xor(bv, off, 64);
                    int    oi = __shfl_xor(bi, off, 64);
                    if (ov > bv || (ov == bv && oi < bi)) { bv = ov; bi = oi; }
                }
                if (lane == 0) {
                    const size_t T = (size_t)tok;
                    out[T * TOPK + r] = (float)(exp(bv - mx) / s);
                    out[(size_t)TOKENS * TOPK + T * TOPK + r] = (float)bi;
                }
                if (bi == e1) w1 = -1e300;
                if (bi == e2) w2 = -1e300;
            }
        }
    }
}

// ====== fallback (verified R4): fp32 vector GEMM + topk + flag ======
#define TM     64
#define BK     32
#define STR    33
#define NC     (DDIM / BK)

__global__ __launch_bounds__(256, 4)
void gemm_topk(const float* __restrict__ x,
               const float* __restrict__ W,
               const float* __restrict__ b,
               float* __restrict__ out,
               unsigned int* __restrict__ flagc,
               unsigned int* __restrict__ flagl)
{
    __shared__ __align__(16) float smem[TM * NEXP];
    float* xs = smem;
    float* ws = smem + TM * STR;
    float* lg = smem;

    const int t    = threadIdx.x;
    const int tok0 = blockIdx.x * TM;
    const int el   = t >> 3;
    const int tg   = t & 7;

    float acc[8][4];
    #pragma unroll
    for (int i = 0; i < 8; ++i)
        #pragma unroll
        for (int j = 0; j < 4; ++j) acc[i][j] = 0.0f;

    float4 gx[2], gw[4];
    {
        #pragma unroll
        for (int r = 0; r < 2; ++r) {
            const int q = t + r * 256;
            gx[r] = *reinterpret_cast<const float4*>(
                &x[(size_t)(tok0 + (q >> 3)) * DDIM + (q & 7) * 4]);
        }
        #pragma unroll
        for (int r = 0; r < 4; ++r) {
            const int q = t + r * 256;
            gw[r] = *reinterpret_cast<const float4*>(
                &W[(size_t)(q >> 3) * DDIM + (q & 7) * 4]);
        }
    }

    #pragma unroll 1
    for (int c = 0; c < NC; ++c) {
        __syncthreads();
        #pragma unroll
        for (int r = 0; r < 2; ++r) {
            const int q = t + r * 256;
            *reinterpret_cast<float4*>(&xs[(q >> 3) * STR + (q & 7) * 4]) = gx[r];
        }
        #pragma unroll
        for (int r = 0; r < 4; ++r) {
            const int q = t + r * 256;
            *reinterpret_cast<float4*>(&ws[(q >> 3) * STR + (q & 7) * 4]) = gw[r];
        }
        __syncthreads();
        if (c + 1 < NC) {
            const int k0 = (c + 1) * BK;
            #pragma unroll
            for (int r = 0; r < 2; ++r) {
                const int q = t + r * 256;
                gx[r] = *reinterpret_cast<const float4*>(
                    &x[(size_t)(tok0 + (q >> 3)) * DDIM + k0 + (q & 7) * 4]);
            }
            #pragma unroll
            for (int r = 0; r < 4; ++r) {
                const int q = t + r * 256;
                gw[r] = *reinterpret_cast<const float4*>(
                    &W[(size_t)(q >> 3) * DDIM + k0 + (q & 7) * 4]);
            }
        }
        #pragma unroll 2
        for (int kk = 0; kk < BK; kk += 4) {
            float4 xa[8], wb[4];
            #pragma unroll
            for (int i = 0; i < 8; ++i)
                xa[i] = *reinterpret_cast<const float4*>(&xs[(tg * 8 + i) * STR + kk]);
            #pragma unroll
            for (int j = 0; j < 4; ++j)
                wb[j] = *reinterpret_cast<const float4*>(&ws[(el * 4 + j) * STR + kk]);
            #pragma unroll
            for (int i = 0; i < 8; ++i) {
                #pragma unroll
                for (int j = 0; j < 4; ++j) {
                    acc[i][j] = fmaf(xa[i].x, wb[j].x, acc[i][j]);
                    acc[i][j] = fmaf(xa[i].y, wb[j].y, acc[i][j]);
                    acc[i][j] = fmaf(xa[i].z, wb[j].z, acc[i][j]);
                    acc[i][j] = fmaf(xa[i].w, wb[j].w, acc[i][j]);
                }
            }
        }
    }

    __syncthreads();
    #pragma unroll
    for (int i = 0; i < 8; ++i)
        #pragma unroll
        for (int j = 0; j < 4; ++j)
            lg[(tg * 8 + i) * NEXP + el * 4 + j] = acc[i][j];
    __syncthreads();

    const int lane = t & 63;
    const int wv   = t >> 6;
    for (int it = 0; it < 16; ++it) {
        const int m  = wv * 16 + it;
        const int e1 = lane, e2 = lane + 64;
        const float v1 = lg[m * NEXP + e1] + b[e1];
        const float v2 = lg[m * NEXP + e2] + b[e2];
        float mx = fmaxf(v1, v2);
        #pragma unroll
        for (int off = 32; off > 0; off >>= 1)
            mx = fmaxf(mx, __shfl_xor(mx, off, 64));
        float s = expf(v1 - mx) + expf(v2 - mx);
        #pragma unroll
        for (int off = 32; off > 0; off >>= 1)
            s += __shfl_xor(s, off, 64);
        float w1 = v1, w2 = v2;
        float prev = 0.0f, mingap = 1e30f;
        for (int r = 0; r < TOPK + 1; ++r) {
            float bv = w1; int bi = e1;
            if (w2 > bv) { bv = w2; bi = e2; }
            #pragma unroll
            for (int off = 32; off > 0; off >>= 1) {
                float ov = __shfl_xor(bv, off, 64);
                int   oi = __shfl_xor(bi, off, 64);
                if (ov > bv || (ov == bv && oi < bi)) { bv = ov; bi = oi; }
            }
            if (r > 0) mingap = fminf(mingap, prev - bv);
            prev = bv;
            if (r < TOPK && lane == 0) {
                const size_t T = (size_t)tok0 + m;
                out[T * TOPK + r] = expf(bv - mx) / s;
                out[(size_t)TOKENS * TOPK + T * TOPK + r] = (float)bi;
            }
            if (bi == e1) w1 = -1e30f;
            if (bi == e2) w2 = -1e30f;
        }
        if (lane == 0 && mingap < DELTA) {
            unsigned int pos = atomicAdd(flagc, 1u);
            if (pos < FCAP) flagl[pos] = (unsigned int)(tok0 + m);
        }
    }
}

extern "C" void kernel_launch(void* const* d_in, const int* in_sizes, int n_in,
                              void* d_out, int out_size, void* d_ws, size_t ws_size,
                              hipStream_t stream) {
    const float* x = (const float*)d_in[0];
    const float* W = (const float*)d_in[1];
    const float* b = (const float*)d_in[2];
    float* out = (float*)d_out;

    unsigned int* flagc = (unsigned int*)d_ws;
    unsigned int* flagl = (unsigned int*)((char*)d_ws + 64);
    uint4*        wimg  = (uint4*)((char*)d_ws + 65536);

    const size_t need = 65536 + (size_t)128 * 8 * 2 * 64 * 16;  // flags + 2MB wimg

    hipMemsetAsync(flagc, 0, 4, stream);
    if (ws_size >= need) {
        hipLaunchKernelGGL(split_w,   dim3(128),        dim3(256), 0, stream, W, wimg);
        hipLaunchKernelGGL(gemm_mfma, dim3(TOKENS / 32), dim3(256), 0, stream,
                           x, wimg, b, out, flagc, flagl);
    } else {
        hipLaunchKernelGGL(gemm_topk, dim3(TOKENS / TM), dim3(256), 0, stream,
                           x, W, b, out, flagc, flagl);
    }
    hipLaunchKernelGGL(refine, dim3(128), dim3(256), 0, stream,
                       x, W, b, out, flagc, flagl);
}